// Round 1
// baseline (337.984 us; speedup 1.0000x reference)
//
#include <hip/hip_runtime.h>

// Attention fwd: B=8, SQ=SK=2048, D=512, fp32 in/out, no scaling, no mask.
// Plan: prepass K->fp16, V->fp16 transposed (+key-pair interleave perm);
// fused flash kernel: 4 waves x 16 q-rows, KV tile = 32 keys, double-buffered
// LDS staging via global_load_lds(16B), XOR-swizzled LDS layouts, fp32 online
// softmax, mfma_f32_16x16x32_f16 for QK^T and PV.

#define B_   8
#define SQ_  2048
#define SK_  2048
#define D_   512
#define KV   32
#define NT   (SK_/KV)   // 64 tiles

typedef _Float16 f16;
typedef f16  f16x8 __attribute__((ext_vector_type(8)));
typedef float f32x4 __attribute__((ext_vector_type(4)));
typedef unsigned short u16;
typedef unsigned int   u32;

#define MFMA16(a,b,c) __builtin_amdgcn_mfma_f32_16x16x32_f16(a,b,c,0,0,0)

__device__ __forceinline__ void gload16(const void* g, void* l){
  // async global->LDS, 16B per lane; LDS dest = wave-uniform base + lane*16
  __builtin_amdgcn_global_load_lds(
      (__attribute__((address_space(1))) void*)(g),
      (__attribute__((address_space(3))) void*)(l), 16, 0, 0);
}

// ---------- prepass 1: K fp32 -> fp16, row-major [b][k][d] ----------
__global__ __launch_bounds__(256) void kconv(const float* __restrict__ src,
                                             u16* __restrict__ dst){
  size_t i = ((size_t)blockIdx.x*256 + threadIdx.x)*8;
  float4 a = *(const float4*)(src + i);
  float4 b = *(const float4*)(src + i + 4);
  union { f16 h[8]; uint4 v; } r;
  r.h[0]=(f16)a.x; r.h[1]=(f16)a.y; r.h[2]=(f16)a.z; r.h[3]=(f16)a.w;
  r.h[4]=(f16)b.x; r.h[5]=(f16)b.y; r.h[6]=(f16)b.z; r.h[7]=(f16)b.w;
  *(uint4*)(dst + i) = r.v;
}

// ---------- prepass 2: V fp32 [b][k][d] -> Vt fp16 [b][d][pos] ----------
// pos within each 32-key tile holds key perm(p) = (p&1)*16 + (p>>1), so the
// attn kernel can pack P pairs (key c, key c+16) as adjacent half2.
__global__ __launch_bounds__(256) void vtrans(const float* __restrict__ V,
                                              u16* __restrict__ Vt){
  __shared__ float t[32][33];           // +1 pad: conflict-free permuted read
  int b = blockIdx.z, k0 = blockIdx.x*32, d0 = blockIdx.y*32;
  int tx = threadIdx.x & 31, ty = threadIdx.x >> 5;
  const float* vp = V + ((size_t)b*SK_ + k0)*D_ + d0;
  #pragma unroll
  for (int i=0;i<4;i++) t[ty+i*8][tx] = vp[(size_t)(ty+i*8)*D_ + tx];
  __syncthreads();
  int key = ((tx&1)<<4) | (tx>>1);      // perm(tx)
  u16* op = Vt + ((size_t)b*D_ + d0)*SK_ + k0;
  #pragma unroll
  for (int i=0;i<4;i++){
    int dd = ty+i*8;
    f16 h = (f16)t[key][dd];
    op[(size_t)dd*SK_ + tx] = __builtin_bit_cast(u16, h);
  }
}

// ---------- fused attention ----------
// grid (SQ/64, B), 256 threads (4 waves). wave w owns q-rows [blk*64+w*16, +16).
// LDS: K dbuf 2x32KB ([32 key][1024B], slot^key&7 swizzle via source addr),
//      V dbuf 2x32KB ([512 d][64B], slot^(d>>1)&3), P 4x1KB ([16 row][64B],
//      slot^(row>>1)&3). total 132KB -> 1 block/CU.
__global__ __launch_bounds__(256,1) void attn(const float* __restrict__ Q,
      const u16* __restrict__ K16, const u16* __restrict__ Vt16,
      float* __restrict__ Out){
  __shared__ __align__(16) unsigned char sm[135168];
  const int tid = threadIdx.x;
  const int w = tid>>6, l = tid&63;
  const int c = l&15, g = l>>4;
  const int b = blockIdx.y;
  const int qrow0 = blockIdx.x*64 + w*16;

  // Q fragments in registers: A-frag lane(c,g): Q[qrow0+c][ds*32+g*8 .. +7]
  f16x8 qf[16];
  {
    const float* qp = Q + ((size_t)b*SQ_ + qrow0 + c)*D_ + g*8;
    #pragma unroll
    for (int ds=0; ds<16; ds++){
      float4 a  = *(const float4*)(qp + ds*32);
      float4 b4 = *(const float4*)(qp + ds*32 + 4);
      f16x8 h;
      h[0]=(f16)a.x;  h[1]=(f16)a.y;  h[2]=(f16)a.z;  h[3]=(f16)a.w;
      h[4]=(f16)b4.x; h[5]=(f16)b4.y; h[6]=(f16)b4.z; h[7]=(f16)b4.w;
      qf[ds]=h;
    }
  }

  f32x4 o[32];
  #pragma unroll
  for (int i=0;i<32;i++) o[i] = (f32x4){0.f,0.f,0.f,0.f};
  float m[4]  = {-3e38f,-3e38f,-3e38f,-3e38f};
  float ls[4] = {0.f,0.f,0.f,0.f};

  const unsigned char* kg = (const unsigned char*)(K16  + (size_t)b*SK_*D_);
  const unsigned char* vg = (const unsigned char*)(Vt16 + (size_t)b*D_*SK_);
  const int vswz = ((l&3) ^ ((l>>3)&3))*16;   // V stage source-slot swizzle
  const int fsw  = (g ^ ((c>>1)&3))*16;       // V/P frag read swizzle

  auto stage = [&](int t, int buf){
    // K tile: 32 rows x 1KB, contiguous in ws; swizzle via per-lane source
    const unsigned char* kt = kg + (size_t)t*(KV*1024);
    unsigned char* Kl = sm + buf*32768;
    #pragma unroll
    for (int i=0;i<8;i++){
      int r = w*8 + i;                        // r&7 == i
      gload16(kt + r*1024 + ((l ^ i)*16), Kl + r*1024);
    }
    // V tile: [512 d][64B] slice of Vt (row stride 4096B)
    const unsigned char* vt = vg + (size_t)t*(KV*2);
    unsigned char* Vl = sm + 65536 + buf*32768;
    #pragma unroll
    for (int i=0;i<8;i++){
      int s = w*8 + i;
      int d = s*16 + (l>>2);
      gload16(vt + (size_t)d*(SK_*2) + vswz, Vl + s*1024);
    }
  };

  stage(0, 0);
  #pragma unroll 1
  for (int t=0; t<NT; t++){
    const int cur = t&1;
    if (t+1 < NT){
      stage(t+1, cur^1);                      // prefetch flies over compute(t)
      asm volatile("s_waitcnt vmcnt(16)" ::: "memory");  // tile t landed
    } else {
      asm volatile("s_waitcnt vmcnt(0)" ::: "memory");
    }
    __builtin_amdgcn_s_barrier();

    const unsigned char* Kl = sm + cur*32768;
    const unsigned char* Vl = sm + 65536 + cur*32768;
    unsigned char* Pw = sm + 131072 + w*1024; // wave-private P scratch

    // ---- QK^T: S[16 rows][32 keys], fp32 acc
    f32x4 s0 = {0.f,0.f,0.f,0.f}, s1 = {0.f,0.f,0.f,0.f};
    #pragma unroll
    for (int ds=0; ds<16; ds++){
      int off = ((ds*4 + g) ^ (c&7))*16;      // physical slot (swizzled)
      f16x8 kf0 = *(const f16x8*)(Kl + c*1024 + off);
      f16x8 kf1 = *(const f16x8*)(Kl + (c+16)*1024 + off);
      s0 = MFMA16(qf[ds], kf0, s0);
      s1 = MFMA16(qf[ds], kf1, s1);
    }

    // ---- online softmax (C layout: col=key=c(+16), row=g*4+j)
    float rm[4];
    #pragma unroll
    for (int j=0;j<4;j++){
      float v = fmaxf(s0[j], s1[j]);
      v = fmaxf(v, __shfl_xor(v,1));
      v = fmaxf(v, __shfl_xor(v,2));
      v = fmaxf(v, __shfl_xor(v,4));
      v = fmaxf(v, __shfl_xor(v,8));
      rm[j] = v;
    }
    bool grow = (rm[0]>m[0])|(rm[1]>m[1])|(rm[2]>m[2])|(rm[3]>m[3]);
    if (__any(grow)){
      float sc[4];
      #pragma unroll
      for (int j=0;j<4;j++){
        float mn = fmaxf(m[j], rm[j]);
        sc[j] = __expf(m[j]-mn);
        m[j] = mn;
        ls[j] *= sc[j];
      }
      #pragma unroll
      for (int i=0;i<32;i++){
        o[i][0]*=sc[0]; o[i][1]*=sc[1]; o[i][2]*=sc[2]; o[i][3]*=sc[3];
      }
    }
    #pragma unroll
    for (int j=0;j<4;j++){
      float p0 = __expf(s0[j]-m[j]);
      float p1 = __expf(s1[j]-m[j]);
      float su = p0+p1;
      su += __shfl_xor(su,1);
      su += __shfl_xor(su,2);
      su += __shfl_xor(su,4);
      su += __shfl_xor(su,8);
      ls[j] += su;
      // pack keys (c, c+16) -> positions (2c, 2c+1); swizzled b32 store
      int row = g*4+j;
      u32 pv = (u32)__builtin_bit_cast(u16,(f16)p0)
             | ((u32)__builtin_bit_cast(u16,(f16)p1)<<16);
      *(u32*)(Pw + row*64 + (((c>>2) ^ ((row>>1)&3))*16) + (c&3)*4) = pv;
    }

    // ---- PV: O[16][512] += P[16][32] * V'[32][512]
    f16x8 pf = *(const f16x8*)(Pw + c*64 + fsw);
    #pragma unroll
    for (int ct=0; ct<32; ct++){
      int dcol = ct*16 + c;
      f16x8 vf = *(const f16x8*)(Vl + dcol*64 + fsw);  // (dcol>>1)&3==(c>>1)&3
      o[ct] = MFMA16(pf, vf, o[ct]);
    }
    __builtin_amdgcn_s_barrier();             // safe to overwrite buf cur next
  }

  // ---- epilogue: normalize and store
  float inv[4];
  #pragma unroll
  for (int j=0;j<4;j++) inv[j] = 1.f/ls[j];
  float* ob = Out + ((size_t)b*SQ_ + qrow0)*D_;
  #pragma unroll
  for (int ct=0; ct<32; ct++){
    #pragma unroll
    for (int j=0;j<4;j++){
      ob[(size_t)(g*4+j)*D_ + ct*16 + c] = o[ct][j]*inv[j];
    }
  }
}

extern "C" void kernel_launch(void* const* d_in, const int* in_sizes, int n_in,
                              void* d_out, int out_size, void* d_ws, size_t ws_size,
                              hipStream_t stream){
  const float* Q = (const float*)d_in[0];
  const float* K = (const float*)d_in[1];
  const float* V = (const float*)d_in[2];
  float* out = (float*)d_out;
  u16* K16  = (u16*)d_ws;                               // 16.8 MB
  u16* Vt16 = K16 + (size_t)B_*SK_*D_;                  // 16.8 MB

  kconv <<<dim3((B_*SK_*D_)/(256*8)), 256, 0, stream>>>(K, K16);
  vtrans<<<dim3(SK_/32, D_/32, B_),  256, 0, stream>>>(V, Vt16);
  attn  <<<dim3(SQ_/64, B_),         256, 0, stream>>>(Q, K16, Vt16, out);
}

// Round 2
// 272.708 us; speedup vs baseline: 1.2394x; 1.2394x over previous
//
#include <hip/hip_runtime.h>

// Attention fwd: B=8, SQ=SK=2048, D=512, fp32 in/out, no scaling, no mask.
// Design E: 8 waves (512 thr), QBLK=64 rows/block, KVBLK=64.
//  - QK: wave (wr,wc) computes S[16 rows][32 keys]; Q in regs, K in LDS dbuf.
//  - PV: D-split — wave w owns d-cols [64w,64w+64) for ALL 64 rows; V read
//    directly from global in frag-linear layout (1KB contiguous per frag),
//    L2-resident per XCD (batch == XCD via blockIdx swizzle).
//  - P + softmax stats shared via LDS; 3 raw s_barriers/tile with targeted
//    lgkmcnt waits only (K-prefetch vmcnt rides across barriers).

#define B_   8
#define SQ_  2048
#define SK_  2048
#define D_   512
#define KV   64
#define NT   (SK_/KV)   // 32 tiles

typedef _Float16 f16;
typedef f16  f16x8 __attribute__((ext_vector_type(8)));
typedef float f32x4 __attribute__((ext_vector_type(4)));
typedef unsigned short u16;
typedef unsigned int   u32;

#define MFMA16(a,b,c) __builtin_amdgcn_mfma_f32_16x16x32_f16(a,b,c,0,0,0)

__device__ __forceinline__ void gload16(const void* g, void* l){
  __builtin_amdgcn_global_load_lds(
      (__attribute__((address_space(1))) void*)(g),
      (__attribute__((address_space(3))) void*)(l), 16, 0, 0);
}

// ---------- prepass 1: K fp32 -> fp16, row-major [b][k][d] ----------
__global__ __launch_bounds__(256) void kconv(const float* __restrict__ src,
                                             u16* __restrict__ dst){
  size_t i = ((size_t)blockIdx.x*256 + threadIdx.x)*8;
  float4 a = *(const float4*)(src + i);
  float4 b = *(const float4*)(src + i + 4);
  union { f16 h[8]; uint4 v; } r;
  r.h[0]=(f16)a.x; r.h[1]=(f16)a.y; r.h[2]=(f16)a.z; r.h[3]=(f16)a.w;
  r.h[4]=(f16)b.x; r.h[5]=(f16)b.y; r.h[6]=(f16)b.z; r.h[7]=(f16)b.w;
  *(uint4*)(dst + i) = r.v;
}

// ---------- prepass 2: V fp32 [b][k][d] -> frag-linear fp16 ----------
// Layout: [b][kchunk 64][ctg 32][g 4][c 16][j 8] where within a 32-key chunk,
// position p = g*8+j holds key perm(p) = (p&1)*16 + (p>>1) (pair-interleave
// so the attn kernel packs P pairs (key c, key c+16) as adjacent half2).
// One B-frag for MFMA = 1KB contiguous (lane l=(c,g) reads 16B at l*16).
__global__ __launch_bounds__(256) void vtrans(const float* __restrict__ V,
                                              u16* __restrict__ Vt){
  __shared__ float tile[32][33];
  int b = blockIdx.z, kcb = blockIdx.x, ctg0 = blockIdx.y*2;  // d0 = ctg0*16
  int tx = threadIdx.x & 31, ty = threadIdx.x >> 5;
  const float* vp = V + ((size_t)b*SK_ + (size_t)kcb*32)*D_ + ctg0*16;
  #pragma unroll
  for (int i=0;i<4;i++) tile[ty+i*8][tx] = vp[(size_t)(ty+i*8)*D_ + tx];
  __syncthreads();
  unsigned char* ob = (unsigned char*)(Vt + (size_t)b*SK_*D_);
  #pragma unroll
  for (int i=0;i<4;i++){
    int e = threadIdx.x + 256*i;          // 0..1023 elements (2 chunks x 512)
    int chunk = e >> 9;                   // which ctg of this block
    int rem = e & 511;                    // g*128 + cc*8 + j
    int gq = rem >> 7, cc = (rem>>3)&15, j = rem&7;
    int p = gq*8 + j;
    int key = ((p&1)<<4) | (p>>1);
    int dd = chunk*16 + cc;
    f16 h = (f16)tile[key][dd];
    size_t off = (size_t)(kcb*32 + ctg0 + chunk)*1024 + (size_t)rem*2;
    *(u16*)(ob + off) = __builtin_bit_cast(u16, h);
  }
}

// ---------- fused attention ----------
// LDS map: K dbuf [2][64 rows][1024B] = 131072; P [64 rows][128B] = 8192
// (@131072); stats @139264: pmax[2][64], psum[2][64], allm[2][64],
// scale[64], alll[64]. Total 141312 B -> 1 block/CU, 8 waves = 2/SIMD.
__global__ __launch_bounds__(512,2) void attn(const float* __restrict__ Q,
      const u16* __restrict__ K16, const u16* __restrict__ Vt16,
      float* __restrict__ Out){
  __shared__ __align__(16) unsigned char sm[141312];
  const int tid = threadIdx.x;
  const int w  = tid>>6, l = tid&63;
  const int c  = l&15,  g = l>>4;
  const int c7 = c&7;
  const int wr = w&3,  wc = w>>2;
  const int b  = blockIdx.x & 7;          // batch == XCD (L2 locality)
  const int qt = blockIdx.x >> 3;
  const int row0 = wr*16;                 // wave's S-row base within block

  float* pmaxL  = (float*)(sm + 139264);  // [2][64]
  float* psumL  = (float*)(sm + 139776);  // [2][64]
  float* allmL  = (float*)(sm + 140288);  // [2][64]
  float* scaleL = (float*)(sm + 140800);  // [64]
  float* alllL  = (float*)(sm + 141056);  // [64]

  // ---- Q fragments: lane(c,g) holds Q[row0+c][ds*32 + g*8 .. +7]
  f16x8 qf[16];
  {
    const float* qp = Q + ((size_t)b*SQ_ + (size_t)qt*64 + row0 + c)*D_ + g*8;
    #pragma unroll
    for (int ds=0; ds<16; ds++){
      float4 a  = *(const float4*)(qp + ds*32);
      float4 b4 = *(const float4*)(qp + ds*32 + 4);
      f16x8 h;
      h[0]=(f16)a.x;  h[1]=(f16)a.y;  h[2]=(f16)a.z;  h[3]=(f16)a.w;
      h[4]=(f16)b4.x; h[5]=(f16)b4.y; h[6]=(f16)b4.z; h[7]=(f16)b4.w;
      qf[ds]=h;
    }
  }

  f32x4 o[4][4];
  #pragma unroll
  for (int rt=0;rt<4;rt++)
    #pragma unroll
    for (int ct=0;ct<4;ct++) o[rt][ct]=(f32x4){0.f,0.f,0.f,0.f};

  const unsigned char* kg = (const unsigned char*)(K16  + (size_t)b*SK_*D_);
  const unsigned char* vg = (const unsigned char*)(Vt16 + (size_t)b*SK_*D_);

  auto stage = [&](int t, int buf){
    const unsigned char* kt = kg + (size_t)t*(KV*1024);
    unsigned char* Kl = sm + buf*65536;
    #pragma unroll
    for (int i=0;i<8;i++){
      int r = w*8 + i;                    // r&7 == i
      gload16(kt + (size_t)r*1024 + ((l ^ i)*16), Kl + r*1024);
    }
  };

  stage(0, 0);
  asm volatile("s_waitcnt vmcnt(0)" ::: "memory");
  __builtin_amdgcn_s_barrier();
  asm volatile("" ::: "memory");

  #pragma unroll 1
  for (int t=0; t<NT; t++){
    const int cur = t&1;

    // V fragments for this tile: 8 x 1KB contiguous global loads (L2-hot)
    f16x8 vf[2][4];
    #pragma unroll
    for (int kc=0;kc<2;kc++)
      #pragma unroll
      for (int ct=0;ct<4;ct++)
        vf[kc][ct] = *(const f16x8*)(vg
            + (size_t)((t*2+kc)*32 + w*4 + ct)*1024 + l*16);

    if (t+1 < NT) stage(t+1, cur^1);      // prefetch rides across barriers

    // ---- QK^T: S[16 rows][32 keys]
    const unsigned char* kb0 = sm + cur*65536 + (wc*32 + c)*1024;
    f32x4 s0={0.f,0.f,0.f,0.f}, s1={0.f,0.f,0.f,0.f};
    #pragma unroll
    for (int ds=0; ds<16; ds++){
      int off = ((ds*4+g) ^ c7)*16;       // source-swizzled octet slot
      f16x8 kf0 = *(const f16x8*)(kb0 + off);
      f16x8 kf1 = *(const f16x8*)(kb0 + 16384 + off);
      s0 = MFMA16(qf[ds], kf0, s0);
      s1 = MFMA16(qf[ds], kf1, s1);
    }

    // ---- row max (C layout: col=key=c(+16), row=g*4+j)
    float rm[4];
    #pragma unroll
    for (int j=0;j<4;j++){
      float v = fmaxf(s0[j], s1[j]);
      v = fmaxf(v, __shfl_xor(v,1));
      v = fmaxf(v, __shfl_xor(v,2));
      v = fmaxf(v, __shfl_xor(v,4));
      v = fmaxf(v, __shfl_xor(v,8));
      rm[j] = v;
    }
    if (c==0){
      #pragma unroll
      for (int j=0;j<4;j++) pmaxL[wc*64 + row0 + g*4 + j] = rm[j];
    }
    asm volatile("s_waitcnt lgkmcnt(0)" ::: "memory");
    __builtin_amdgcn_s_barrier();                       // b1: pmax visible
    asm volatile("" ::: "memory");

    // ---- m_new, P = exp(S-m), partial sums
    float mn[4], mpv[4];
    #pragma unroll
    for (int j=0;j<4;j++){
      int r = row0 + g*4 + j;
      float mp = (t==0) ? -3e38f : allmL[cur*64 + r];
      mpv[j] = mp;
      mn[j] = fmaxf(fmaxf(pmaxL[r], pmaxL[64+r]), mp);
    }
    #pragma unroll
    for (int j=0;j<4;j++){
      int r = row0 + g*4 + j;
      float p0 = __expf(s0[j]-mn[j]);
      float p1 = __expf(s1[j]-mn[j]);
      float su = p0+p1;
      su += __shfl_xor(su,1);
      su += __shfl_xor(su,2);
      su += __shfl_xor(su,4);
      su += __shfl_xor(su,8);
      if (c==0) psumL[wc*64 + r] = su;
      // pack keys (c, c+16) -> positions (2c, 2c+1); XOR-swizzled b32 store
      u32 pv = (u32)__builtin_bit_cast(u16,(f16)p0)
             | ((u32)__builtin_bit_cast(u16,(f16)p1)<<16);
      *(u32*)(sm + 131072 + r*128
              + (((wc*4 + (c>>2)) ^ (r&7))*16) + (c&3)*4) = pv;
    }
    float scv[4];
    if (wc==0 && c==0){                   // stats owner: rows row0..row0+16
      #pragma unroll
      for (int j=0;j<4;j++){
        int r = row0 + g*4 + j;
        scv[j] = (t==0) ? 1.f : __expf(mpv[j]-mn[j]);
        scaleL[r] = scv[j];
        allmL[(cur^1)*64 + r] = mn[j];
      }
    }
    asm volatile("s_waitcnt lgkmcnt(0)" ::: "memory");
    __builtin_amdgcn_s_barrier();                       // b2: P/scale visible
    asm volatile("" ::: "memory");

    // ---- rescale O (all 64 rows live in every wave's O)
    if (t>0){
      float sc[4][4];
      bool need=false;
      #pragma unroll
      for (int rt=0;rt<4;rt++)
        #pragma unroll
        for (int j=0;j<4;j++){
          sc[rt][j] = scaleL[rt*16 + g*4 + j];
          need |= (sc[rt][j] != 1.f);
        }
      if (__any(need)){
        #pragma unroll
        for (int rt=0;rt<4;rt++)
          #pragma unroll
          for (int ct=0;ct<4;ct++)
            #pragma unroll
            for (int j=0;j<4;j++) o[rt][ct][j] *= sc[rt][j];
      }
    }
    if (wc==0 && c==0){                   // owner folds l update
      #pragma unroll
      for (int j=0;j<4;j++){
        int r = row0 + g*4 + j;
        float base = (t==0) ? 0.f : alllL[r]*scv[j];
        alllL[r] = base + psumL[r] + psumL[64+r];
      }
    }

    // ---- PV: O[64 rows][64 d-slice] += P[64][64] * V'[64][d-slice]
    #pragma unroll
    for (int kc=0;kc<2;kc++){
      f16x8 pa[4];
      #pragma unroll
      for (int rt=0;rt<4;rt++)
        pa[rt] = *(const f16x8*)(sm + 131072 + (rt*16+c)*128
                                 + (((kc*4+g) ^ c7)*16));
      #pragma unroll
      for (int rt=0;rt<4;rt++)
        #pragma unroll
        for (int ct=0;ct<4;ct++)
          o[rt][ct] = MFMA16(pa[rt], vf[kc][ct], o[rt][ct]);
    }

    asm volatile("s_waitcnt vmcnt(0) lgkmcnt(0)" ::: "memory");
    __builtin_amdgcn_s_barrier();                       // b3: K(t+1) landed
    asm volatile("" ::: "memory");
  }

  // ---- epilogue: normalize and store (wave's d-slice = [64w, 64w+64))
  float inv[4][4];
  #pragma unroll
  for (int rt=0;rt<4;rt++)
    #pragma unroll
    for (int j=0;j<4;j++)
      inv[rt][j] = 1.f / alllL[rt*16 + g*4 + j];
  float* ob = Out + ((size_t)b*SQ_ + (size_t)qt*64)*D_ + (size_t)w*64;
  #pragma unroll
  for (int rt=0;rt<4;rt++)
    #pragma unroll
    for (int ct=0;ct<4;ct++)
      #pragma unroll
      for (int j=0;j<4;j++)
        ob[(size_t)(rt*16 + g*4 + j)*D_ + ct*16 + c] = o[rt][ct][j]*inv[rt][j];
}

extern "C" void kernel_launch(void* const* d_in, const int* in_sizes, int n_in,
                              void* d_out, int out_size, void* d_ws, size_t ws_size,
                              hipStream_t stream){
  const float* Q = (const float*)d_in[0];
  const float* K = (const float*)d_in[1];
  const float* V = (const float*)d_in[2];
  float* out = (float*)d_out;
  u16* K16  = (u16*)d_ws;                               // 16.8 MB
  u16* Vt16 = K16 + (size_t)B_*SK_*D_;                  // 16.8 MB

  kconv <<<dim3((B_*SK_*D_)/(256*8)),   256, 0, stream>>>(K, K16);
  vtrans<<<dim3(SK_/32, D_/32, B_),     256, 0, stream>>>(V, Vt16);
  attn  <<<dim3((SQ_/64)*B_),           512, 0, stream>>>(Q, K16, Vt16, out);
}

// Round 7
// 213.438 us; speedup vs baseline: 1.5835x; 1.2777x over previous
//
#include <hip/hip_runtime.h>

// Attention fwd: B=8, SQ=SK=2048, D=512, fp32 in/out, no scaling, no mask.
// Design G (producer-consumer):
//   prepasses: K -> f16 rows (kconv); V -> f16 B-frag-linear (vtrans).
//   attn: 8 waves. Waves 0-3 = QK producers: Q loaded fp32->f16 into regs
//   (128 VGPR), K in LDS dbuf (global_load_lds, source-swizzled), swapped
//   mfma_32x32x16_f16 (A=K, B=Q -> C[key][qrow]), in-register softmax (lane
//   owns a q-row), in-register P repack (cvt_pkrtz + shfl_xor(32)) -> P LDS
//   (dbuf, swizzled). Waves 4-7 = PV consumers: each owns a 128-wide d-slice
//   for all 64 rows (O = 128 VGPR), V frags read directly from global
//   (L2-resident, XCD-pinned batch), P A-frags from LDS. 2 raw barriers/step;
//   K-prefetch vmcnt rides across barriers.

#define B_   8
#define SQ_  2048
#define SK_  2048
#define D_   512
#define KV   64
#define NT   (SK_/KV)   // 32 tiles

typedef _Float16 f16;
typedef f16  f16x8 __attribute__((ext_vector_type(8)));
typedef float f32x16 __attribute__((ext_vector_type(16)));
typedef unsigned short u16;
typedef unsigned int   u32;

#define MFMA32(a,b,c) __builtin_amdgcn_mfma_f32_32x32x16_f16(a,b,c,0,0,0)

#define BAR() do{ asm volatile("s_waitcnt lgkmcnt(0)" ::: "memory"); \
                  __builtin_amdgcn_s_barrier(); \
                  asm volatile("" ::: "memory"); }while(0)

__device__ __forceinline__ void gload16(const void* g, void* l){
  __builtin_amdgcn_global_load_lds(
      (const __attribute__((address_space(1))) void*)(g),
      (__attribute__((address_space(3))) void*)(l), 16, 0, 0);
}

__device__ __forceinline__ u32 pkf16(float a, float b){
  auto t = __builtin_amdgcn_cvt_pkrtz(a, b);   // __fp16 ext_vector_type(2)
  return __builtin_bit_cast(u32, t);
}

// ---------- prepass 1: K fp32 -> fp16 rows [b][key][d], RTN ----------
__global__ __launch_bounds__(256) void kconv(const float* __restrict__ src,
                                             u16* __restrict__ dst){
  size_t i = ((size_t)blockIdx.x*256 + threadIdx.x)*8;
  float4 a = *(const float4*)(src + i);
  float4 b = *(const float4*)(src + i + 4);
  union { f16 h[8]; uint4 v; } r;
  r.h[0]=(f16)a.x; r.h[1]=(f16)a.y; r.h[2]=(f16)a.z; r.h[3]=(f16)a.w;
  r.h[4]=(f16)b.x; r.h[5]=(f16)b.y; r.h[6]=(f16)b.z; r.h[7]=(f16)b.w;
  *(uint4*)(dst + i) = r.v;
}

// ---------- prepass 2: V fp32 -> f16 B-frag-linear, RTN ----------
// VFL[b][ks128][dt16][lane64][j8] = V[b][ks*16 + (lane>>5)*8 + j]
//                                    [dt*32 + (lane&31)]
__global__ __launch_bounds__(256) void vtrans(const float* __restrict__ V,
                                              u16* __restrict__ VFL){
  __shared__ float tile[16][132];
  int b = blockIdx.z, ks = blockIdx.x, dtg = blockIdx.y;
  int tx = threadIdx.x & 31, ty = threadIdx.x >> 5;
  const float* vp = V + ((size_t)b*SK_ + ks*16)*D_ + dtg*128;
  #pragma unroll
  for (int i=0;i<2;i++){
    int row = ty + i*8;
    float4 v = *(const float4*)(vp + (size_t)row*D_ + tx*4);
    tile[row][tx*4+0]=v.x; tile[row][tx*4+1]=v.y;
    tile[row][tx*4+2]=v.z; tile[row][tx*4+3]=v.w;
  }
  __syncthreads();
  int dt = threadIdx.x>>6, lane = threadIdx.x&63;
  int col = dt*32 + (lane&31), hh = lane>>5;
  union { f16 h[8]; uint4 v; } r;
  #pragma unroll
  for (int j=0;j<8;j++) r.h[j] = (f16)tile[hh*8+j][col];
  unsigned char* ob = (unsigned char*)VFL + (size_t)b*2097152
                    + ((size_t)ks*16 + dtg*4 + dt)*1024;
  *(uint4*)(ob + (size_t)lane*16) = r.v;
}

// ---------- fused attention ----------
// LDS: Kbuf[2][64 rows][1KB] @0 (131072); P[2][64 rows][128B] @131072 (16384);
// pmax[2][64] @147456; psum[2][64] @147968; scale[64] @148480; lfin[64] @148736.
__global__ __launch_bounds__(512,2) void attn(
    const float* __restrict__ Q, const u16* __restrict__ K16,
    const u16* __restrict__ VFL, float* __restrict__ Out){
  __shared__ __align__(16) unsigned char sm[148992];
  const int tid = threadIdx.x;
  const int w = tid>>6, l = tid&63;
  const int l31 = l&31, h = l>>5;
  const int b = blockIdx.x & 7, qt = blockIdx.x >> 3;   // batch == XCD

  float* pmaxL  = (float*)(sm + 147456);
  float* psumL  = (float*)(sm + 147968);
  float* scaleL = (float*)(sm + 148480);
  float* lfinL  = (float*)(sm + 148736);
  unsigned char* Pbuf = sm + 131072;

  if (w < 4){
    // ======== QK producers ========
    const int kt = w & 1, r = w >> 1;
    const int myrow = r*32 + l31;
    const unsigned char* kg = (const unsigned char*)K16 + (size_t)b*2097152;

    // Q fragments: lane(l31,h) holds Q[myrow][ks*16 + h*8 .. +7] (f16)
    f16x8 qf[32];
    {
      const float* qp = Q + ((size_t)b*SQ_ + (size_t)qt*64 + myrow)*D_ + h*8;
      #pragma unroll
      for (int ks=0;ks<32;ks++){
        float4 a  = *(const float4*)(qp + ks*16);
        float4 b4 = *(const float4*)(qp + ks*16 + 4);
        f16x8 hv;
        hv[0]=(f16)a.x;  hv[1]=(f16)a.y;  hv[2]=(f16)a.z;  hv[3]=(f16)a.w;
        hv[4]=(f16)b4.x; hv[5]=(f16)b4.y; hv[6]=(f16)b4.z; hv[7]=(f16)b4.w;
        qf[ks]=hv;
      }
    }

    auto stageK = [&](int tt, int buf){
      const unsigned char* kt_ = kg + (size_t)tt*65536;
      unsigned char* kl = sm + buf*65536;
      #pragma unroll
      for (int i=0;i<16;i++){
        int row = w*16 + i;                 // row&7 == i&7
        gload16(kt_ + (size_t)row*1024 + ((l ^ (i&7))*16), kl + row*1024);
      }
    };

    stageK(0, 0);
    asm volatile("s_waitcnt vmcnt(0)" ::: "memory");
    BAR();                                   // pre-loop

    float m_run = -3e38f, lsum = 0.f, sc_prev = 1.f;

    #pragma unroll 1
    for (int t=0; t<NT; t++){
      const int pb = t&1;
      if (t+1 < NT) stageK(t+1, pb^1);       // prefetch rides across barriers

      f32x16 cacc;
      #pragma unroll
      for (int i=0;i<16;i++) cacc[i] = 0.f;
      const unsigned char* kb = sm + pb*65536 + (size_t)(kt*32 + l31)*1024;
      __builtin_amdgcn_s_setprio(1);
      #pragma unroll
      for (int ks=0;ks<32;ks++){
        f16x8 af = *(const f16x8*)(kb + (((ks*2+h) ^ (l31&7))*16));
        cacc = MFMA32(af, qf[ks], cacc);
      }
      __builtin_amdgcn_s_setprio(0);

      // row max over this wave's 32 keys
      float v = cacc[0];
      #pragma unroll
      for (int i=1;i<16;i++) v = fmaxf(v, cacc[i]);
      v = fmaxf(v, __shfl_xor(v, 32));
      if (h==0) pmaxL[kt*64 + myrow] = v;
      // fold previous step's partial sums into l
      if (t > 0) lsum = lsum*sc_prev + psumL[myrow] + psumL[64+myrow];
      BAR();                                 // A: pmax visible

      float mn = fmaxf(fmaxf(pmaxL[myrow], pmaxL[64+myrow]), m_run);
      float sc = __expf(m_run - mn);
      m_run = mn; sc_prev = sc;
      if (kt==0 && h==0) scaleL[myrow] = sc;
      float p[16]; float su = 0.f;
      #pragma unroll
      for (int i=0;i<16;i++){ p[i] = __expf(cacc[i]-mn); su += p[i]; }
      su += __shfl_xor(su, 32);
      if (h==0) psumL[kt*64 + myrow] = su;

      // pack P to f16 A-layout runs (in-register transpose across halves)
      u32 W[8];
      #pragma unroll
      for (int i=0;i<8;i++) W[i] = pkf16(p[2*i], p[2*i+1]);
      u32 X[8];
      #pragma unroll
      for (int i=0;i<8;i++) X[i] = (u32)__shfl_xor((int)W[i], 32);
      uint4 runA, runB;
      runA.x = h? X[2]:W[0]; runA.y = h? X[3]:W[1];
      runA.z = h? W[2]:X[0]; runA.w = h? W[3]:X[1];
      runB.x = h? X[6]:W[4]; runB.y = h? X[7]:W[5];
      runB.z = h? W[6]:X[4]; runB.w = h? W[7]:X[5];
      unsigned char* pw = Pbuf + pb*8192 + (size_t)myrow*128;
      *(uint4*)(pw + (((kt*4 + h)     ^ (l31&7))*16)) = runA;
      *(uint4*)(pw + (((kt*4 + 2 + h) ^ (l31&7))*16)) = runB;

      asm volatile("s_waitcnt vmcnt(0)" ::: "memory");  // K[t+1] landed
      BAR();                                 // B: P/scale/psum visible
    }
    // tail step
    lsum = lsum*sc_prev + psumL[myrow] + psumL[64+myrow];
    if (kt==0 && h==0) lfinL[myrow] = lsum;
    BAR();                                   // A(NT)
    BAR();                                   // B(NT)
  } else {
    // ======== PV consumers ========
    const int wp = w - 4;                    // d-slice [wp*128, wp*128+128)
    const unsigned char* vg = (const unsigned char*)VFL + (size_t)b*2097152
                            + (size_t)l*16;
    f32x16 o[2][4];
    #pragma unroll
    for (int rt=0;rt<2;rt++)
      #pragma unroll
      for (int dt=0;dt<4;dt++)
        #pragma unroll
        for (int i=0;i<16;i++) o[rt][dt][i] = 0.f;
    f16x8 vf[4][4];
    BAR();                                   // pre-loop

    #pragma unroll 1
    for (int t=0; t<NT; t++){
      if (t >= 1){
        #pragma unroll
        for (int rt=0;rt<2;rt++)
          #pragma unroll
          for (int i=0;i<16;i++){
            float s = scaleL[rt*32 + (i&3) + 8*(i>>2) + 4*h];
            #pragma unroll
            for (int dt=0;dt<4;dt++) o[rt][dt][i] *= s;
          }
      }
      BAR();                                 // A
      if (t >= 1){
        asm volatile("s_waitcnt vmcnt(0)" ::: "memory");  // V[t-1] landed
        const unsigned char* pp = Pbuf + ((t-1)&1)*8192;
        __builtin_amdgcn_s_setprio(1);
        #pragma unroll
        for (int rt=0;rt<2;rt++)
          #pragma unroll
          for (int ksl=0;ksl<4;ksl++){
            f16x8 pa = *(const f16x8*)(pp + (size_t)(rt*32+l31)*128
                        + (((ksl*2+h) ^ (l31&7))*16));
            #pragma unroll
            for (int dt=0;dt<4;dt++)
              o[rt][dt] = MFMA32(pa, vf[ksl][dt], o[rt][dt]);
          }
        __builtin_amdgcn_s_setprio(0);
      }
      // issue V[t] (consumed next step; WAR vs MFMAs safe in-order)
      #pragma unroll
      for (int ksl=0;ksl<4;ksl++)
        #pragma unroll
        for (int dt=0;dt<4;dt++)
          vf[ksl][dt] = *(const f16x8*)(vg
              + (size_t)((t*4+ksl)*16 + wp*4 + dt)*1024);
      BAR();                                 // B
    }
    // tail: consume tile NT-1
    #pragma unroll
    for (int rt=0;rt<2;rt++)
      #pragma unroll
      for (int i=0;i<16;i++){
        float s = scaleL[rt*32 + (i&3) + 8*(i>>2) + 4*h];
        #pragma unroll
        for (int dt=0;dt<4;dt++) o[rt][dt][i] *= s;
      }
    BAR();                                   // A(NT)
    {
      asm volatile("s_waitcnt vmcnt(0)" ::: "memory");
      const unsigned char* pp = Pbuf + ((NT-1)&1)*8192;
      __builtin_amdgcn_s_setprio(1);
      #pragma unroll
      for (int rt=0;rt<2;rt++)
        #pragma unroll
        for (int ksl=0;ksl<4;ksl++){
          f16x8 pa = *(const f16x8*)(pp + (size_t)(rt*32+l31)*128
                      + (((ksl*2+h) ^ (l31&7))*16));
          #pragma unroll
          for (int dt=0;dt<4;dt++)
            o[rt][dt] = MFMA32(pa, vf[ksl][dt], o[rt][dt]);
        }
      __builtin_amdgcn_s_setprio(0);
    }
    BAR();                                   // B(NT): lfin visible

    // normalize + store (d-slice [wp*128, +128))
    float* ob = Out + ((size_t)b*SQ_ + (size_t)qt*64)*D_ + wp*128;
    #pragma unroll
    for (int rt=0;rt<2;rt++)
      #pragma unroll
      for (int i=0;i<16;i++){
        int row = rt*32 + (i&3) + 8*(i>>2) + 4*h;
        float inv = 1.f / lfinL[row];
        #pragma unroll
        for (int dt=0;dt<4;dt++)
          ob[(size_t)row*D_ + dt*32 + l31] = o[rt][dt][i]*inv;
      }
  }
}

extern "C" void kernel_launch(void* const* d_in, const int* in_sizes, int n_in,
                              void* d_out, int out_size, void* d_ws, size_t ws_size,
                              hipStream_t stream){
  const float* Q = (const float*)d_in[0];
  const float* K = (const float*)d_in[1];
  const float* V = (const float*)d_in[2];
  float* out = (float*)d_out;
  u16* K16 = (u16*)d_ws;                         // 16.8 MB
  u16* VFL = K16 + (size_t)8388608;              // 16.8 MB (ws total 33.5 MB)

  kconv <<<dim3(4096),      256, 0, stream>>>(K, K16);
  vtrans<<<dim3(128, 4, 8), 256, 0, stream>>>(V, VFL);
  attn  <<<dim3(256),       512, 0, stream>>>(Q, K16, VFL, out);
}